// Round 13
// baseline (895.318 us; speedup 1.0000x reference)
//
#include <hip/hip_runtime.h>
#include <hip/hip_bf16.h>

// ---------------------------------------------------------------------------
// STD2Vformer forward, MI355X. Round 13 (R12 passed @838us):
//  - gemm operand SWAP (A=X, B=W): D row=n col=ho -> epilogue stores and
//    resid loads are 32B-contiguous (was 8B @ 1KB stride; WRITE 109 vs 59 MB)
//  - XCD-aware 1D grid decode: the 4 ho-blocks sharing an X tile land on the
//    same XCD (lin = r + 224*y, 224%8==0) -> X fetched once per XCD
//  - regT stores now fully coalesced; stats via c-if-chain
// ---------------------------------------------------------------------------

#define NN 883
#define NPAD 896
#define BB 32
#define HH 512
#define NL 10596            // N*L
#define CNT_PER_C 339072.0f // B*N*L
#define TOT_X 1017216       // B*C*N*L
#define LSTR 32             // LDS row stride in shorts (64B)
#define LREG 4096           // shorts per LDS operand region (128*LSTR)

typedef __attribute__((ext_vector_type(8))) short bf16x8;
typedef __attribute__((ext_vector_type(4))) float f32x4;

static __device__ __forceinline__ float bf2f(__hip_bfloat16 v) { return __bfloat162float(v); }
static __device__ __forceinline__ float ldf(const void* p, long i, int f) {
    return f ? ((const float*)p)[i] : bf2f(((const __hip_bfloat16*)p)[i]);
}
static __device__ __forceinline__ unsigned short bfbits(float v) {
    __hip_bfloat16 h = __float2bfloat16(v);
    return *(unsigned short*)&h;
}
static __device__ __forceinline__ void async_copy16(const void* g, void* l) {
    __builtin_amdgcn_global_load_lds((const __attribute__((address_space(1))) void*)g,
                                     (__attribute__((address_space(3))) void*)l, 16, 0, 0);
}

// ---------------- sentinel ----------------
__global__ void k_sent_r13(float* __restrict__ out, int n)
{
    int i = blockIdx.x*256 + threadIdx.x;
    if (i < n) out[i] = 1000.0f;
}

// ---------------- input dtype probe ----------------
__global__ void k_probe_r13(const unsigned short* __restrict__ u, int* __restrict__ flag)
{
    int t = threadIdx.x, cnt = 0;
    for (int i = t; i < 4096; i += 256) {
        int e = (u[i] >> 7) & 0xFF;
        cnt += (e >= 0xC0);
    }
    __shared__ int r[256];
    r[t] = cnt; __syncthreads();
    for (int s = 128; s > 0; s >>= 1) { if (t < s) r[t] += r[t+s]; __syncthreads(); }
    if (t == 0) *flag = (r[0] > 8) ? 1 : 0;
}

// ---------------- finalize: sum P rows of 6 partials ----------------
__global__ void k_fin_r13(const float* __restrict__ pb, int P, float* __restrict__ out)
{
    int t = threadIdx.x;
    float s[6] = {0,0,0,0,0,0};
    for (int r = t; r < P; r += 256)
        #pragma unroll
        for (int j = 0; j < 6; j++) s[j] += pb[r*6 + j];
    __shared__ float red[6][256];
    #pragma unroll
    for (int j = 0; j < 6; j++) red[j][t] = s[j];
    __syncthreads();
    for (int st = 128; st > 0; st >>= 1) {
        if (t < st) {
            #pragma unroll
            for (int j = 0; j < 6; j++) red[j][t] += red[j][t+st];
        }
        __syncthreads();
    }
    if (t < 6) out[t] = red[t][0];
}

// ---------------- weight hi/lo split ----------------
__global__ void k_wsplit_r13(const void* __restrict__ src, const int* __restrict__ dflag,
                             int n, __hip_bfloat16* __restrict__ hi,
                             __hip_bfloat16* __restrict__ lo)
{
    int f = *dflag;
    for (int i = blockIdx.x*256 + threadIdx.x; i < n; i += gridDim.x*256) {
        float v = ldf(src, i, f);
        __hip_bfloat16 h = __float2bfloat16(v);
        hi[i] = h;
        lo[i] = __float2bfloat16(v - bf2f(h));
    }
}

// ---------------- prep ----------------
__global__ void k_prep_r13(const void* __restrict__ seqs, const void* __restrict__ tgts,
                           const void* __restrict__ w0, const void* __restrict__ b0,
                           const void* __restrict__ d2vW, const void* __restrict__ d2vb,
                           const void* __restrict__ fusW, const void* __restrict__ fusb,
                           const void* __restrict__ g1W, const void* __restrict__ g1b,
                           const void* __restrict__ g2W, const void* __restrict__ g2b,
                           const int* __restrict__ dflag,
                           int* __restrict__ tidx, int* __restrict__ didx,
                           float* __restrict__ phi, float* __restrict__ wc)
{
    int f = *dflag, t = threadIdx.x;
    if (t < 32) {
        int b = t;
        float h  = (ldf(seqs, (b*5+3)*12 + 11, f) + 0.5f) * 23.0f;
        float mi = (ldf(seqs, (b*5+4)*12 + 11, f) + 0.5f) * 59.0f;
        int ti = (int)((h * 60.0f + mi) / 5.0f);
        tidx[b] = ti < 0 ? 0 : (ti > 287 ? 287 : ti);
        int di = (int)((ldf(seqs, (b*5+2)*12 + 11, f) + 0.5f) * 6.0f);
        didx[b] = di < 0 ? 0 : (di > 6 ? 6 : di);
    }
    for (int i = t; i < 768; i += 256) {
        int b = i / 24, tt = i % 24;
        float tau[5];
        #pragma unroll
        for (int d = 0; d < 5; d++)
            tau[d] = (tt < 12) ? ldf(seqs, (b*5+d)*12 + tt, f)
                               : ldf(tgts, (b*5+d)*12 + tt - 12, f);
        float s = ldf(b0, 0, f);
        #pragma unroll
        for (int d = 0; d < 5; d++) s += tau[d] * ldf(w0, d, f);
        for (int k = 0; k < 16; k++) {
            float arg = ldf(d2vb, k, f);
            #pragma unroll
            for (int d = 0; d < 5; d++) arg += tau[d] * ldf(d2vW, k*5 + d, f);
            s += sinf(arg);
        }
        phi[i] = s;
    }
    if (t < 24) {
        if (t < 9) {
            int o = t / 3, c = t % 3; float s = 0.f;
            for (int d = 0; d < 128; d++) s += ldf(fusW, c*128+d, f) * ldf(g1W, d*3+o, f);
            wc[t] = s;
        } else if (t < 12) {
            int o = t - 9; float s = ldf(g1b, o, f);
            for (int d = 0; d < 128; d++) s += ldf(fusb, d, f) * ldf(g1W, d*3+o, f);
            wc[9 + o] = s;
        } else if (t < 21) {
            int j = t - 12; int o = j / 3, c = j % 3; float s = 0.f;
            for (int d = 0; d < 128; d++) s += ldf(fusW, c*128+d, f) * ldf(g2W, d*3+o, f);
            wc[12 + j] = s;
        } else {
            int o = t - 21; float s = ldf(g2b, o, f);
            for (int d = 0; d < 128; d++) s += ldf(fusb, d, f) * ldf(g2W, d*3+o, f);
            wc[21 + o] = s;
        }
    }
}

// ---------------- e1 (n-major) and e2t (d-major) ----------------
__global__ void k_e_r13(const void* __restrict__ mb, const void* __restrict__ We1,
                        const void* __restrict__ We2, const int* __restrict__ dflag,
                        float* __restrict__ e1, float* __restrict__ e2t)
{
    int f = *dflag;
    int idx = blockIdx.x*256 + threadIdx.x;
    int which = idx >= 113024;
    int j = which ? idx - 113024 : idx;
    int d = j & 127, n = j >> 7;
    const void* W = which ? We2 : We1;
    float s = 0.f;
    for (int k = 0; k < 128; k++)
        s += ldf(mb, n*128 + k, f) * ldf(W, k*128 + d, f);
    if (which) e2t[d*NN + n] = s;
    else       e1[j] = s;
}

// ---- fused graph ----
__global__ void __launch_bounds__(256)
k_graph_r13(const float* __restrict__ e1, const float* __restrict__ e2t,
            float* __restrict__ topval, int* __restrict__ topidx)
{
    int n = blockIdx.x, t = threadIdx.x;
    __shared__ float e1s[128];
    __shared__ float arow[NN];
    __shared__ float red[256];
    __shared__ int redi[256];
    if (t < 128) e1s[t] = e1[n*128 + t];
    __syncthreads();
    for (int m = t; m < NN; m += 256) {
        float acc = 0.f;
        #pragma unroll 8
        for (int k = 0; k < 128; k++) acc += e1s[k] * e2t[k*NN + m];
        arow[m] = acc;
    }
    __syncthreads();
    float s = 0.f;
    for (int m = t; m < NN; m += 256) s += arow[m];
    red[t] = s; __syncthreads();
    for (int st = 128; st > 0; st >>= 1) { if (t < st) red[t] += red[t+st]; __syncthreads(); }
    float mean = red[0] / 883.0f; __syncthreads();
    float ss = 0.f;
    for (int m = t; m < NN; m += 256) { float d = arow[m] - mean; ss += d*d; }
    red[t] = ss; __syncthreads();
    for (int st = 128; st > 0; st >>= 1) { if (t < st) red[t] += red[t+st]; __syncthreads(); }
    float rstd = 1.0f / sqrtf(red[0] / 882.0f); __syncthreads();
    for (int m = t; m < NN; m += 256) {
        float z = (arow[m] - mean) * rstd;
        z = fmaxf(z, 0.f);
        if (m == n) z -= 1e6f;
        arow[m] = z;
    }
    __syncthreads();
    float mx = -3.4e38f;
    for (int m = t; m < NN; m += 256) mx = fmaxf(mx, arow[m]);
    red[t] = mx; __syncthreads();
    for (int st = 128; st > 0; st >>= 1) { if (t < st) red[t] = fmaxf(red[t], red[t+st]); __syncthreads(); }
    float M = red[0]; __syncthreads();
    float ds = 0.f;
    for (int m = t; m < NN; m += 256) { float e = expf(arow[m] - M); arow[m] = e; ds += e; }
    red[t] = ds; __syncthreads();
    for (int st = 128; st > 0; st >>= 1) { if (t < st) red[t] += red[t+st]; __syncthreads(); }
    float inv = 1.0f / red[0]; __syncthreads();
    for (int m = t; m < NN; m += 256) arow[m] *= inv;
    __syncthreads();
    for (int j = 0; j < 9; j++) {
        float bv = -1.f; int bi = 0;
        for (int m = t; m < NN; m += 256) { float v = arow[m]; if (v > bv) { bv = v; bi = m; } }
        red[t] = bv; redi[t] = bi; __syncthreads();
        for (int st = 128; st > 0; st >>= 1) {
            if (t < st) {
                float ov = red[t+st]; int oi = redi[t+st];
                if (ov > red[t] || (ov == red[t] && oi < redi[t])) { red[t] = ov; redi[t] = oi; }
            }
            __syncthreads();
        }
        if (t == 0) {
            topval[n*9 + j] = red[0];
            topidx[n*9 + j] = redi[0];
            arow[redi[0]] = -1.f;
        }
        __syncthreads();
    }
}

// ---------------- bn1 stats -> partials ----------------
__global__ void k_bn1_r13(const void* __restrict__ x, const int* __restrict__ dflag,
                          float* __restrict__ pb)
{
    int f = *dflag;
    float s[3] = {0,0,0}, q[3] = {0,0,0};
    for (int i = blockIdx.x*256 + threadIdx.x; i < TOT_X; i += 512*256) {
        int c = (i / NL) % 3;
        float v = ldf(x, i, f);
        s[c] += v; q[c] += v*v;
    }
    __shared__ float red[6][256];
    int t = threadIdx.x;
    #pragma unroll
    for (int j = 0; j < 3; j++) { red[j][t] = s[j]; red[3+j][t] = q[j]; }
    __syncthreads();
    for (int st_ = 128; st_ > 0; st_ >>= 1) {
        if (t < st_) {
            #pragma unroll
            for (int j = 0; j < 6; j++) red[j][t] += red[j][t+st_];
        }
        __syncthreads();
    }
    if (t < 6) pb[blockIdx.x*6 + t] = red[t][0];
}

// ---------------- build hidden (hi,lo); 8 nodes/block ----------------
__global__ void __launch_bounds__(256)
k_hid_r13(const void* __restrict__ in, const void* __restrict__ mb,
          const void* __restrict__ tide, const void* __restrict__ diwe,
          const void* __restrict__ tsW, const void* __restrict__ tsb,
          const int* __restrict__ tidx, const int* __restrict__ didx,
          const int* __restrict__ dflag, const float* __restrict__ st1,
          int b0, __hip_bfloat16* __restrict__ Xhi, __hip_bfloat16* __restrict__ Xlo)
{
    int f = *dflag;
    int bl = blockIdx.y, bg = b0 + bl, t = threadIdx.x;
    int n0 = blockIdx.x * 8;
    __shared__ float tsw[128*37];
    __shared__ float tsbs[128];
    __shared__ float xbs[8][36];
    float m1[3], r1v[3];
    #pragma unroll
    for (int c = 0; c < 3; c++) {
        float m = st1[c] * (1.0f/CNT_PER_C);
        float v = st1[3+c] * (1.0f/CNT_PER_C) - m*m;
        m1[c] = m; r1v[c] = 1.0f / sqrtf(v + 1e-5f);
    }
    for (int i = t; i < 4608; i += 256)
        tsw[(i/36)*37 + (i%36)] = ldf(tsW, i, f);
    if (t < 128) tsbs[t] = ldf(tsb, t, f);
    for (int i = t; i < 288; i += 256) {
        int nl = i / 36, k = i % 36;
        int c = k / 12, l = k % 12;
        int n = n0 + nl; if (n >= NN) n = NN - 1;
        xbs[nl][k] = (ldf(in, ((long)(bg*3 + c)*NN + n)*12 + l, f) - m1[c]) * r1v[c];
    }
    __syncthreads();
    int nloc = t >> 5, lane = t & 31;
    int n = n0 + nloc;
    if (n >= NN) return;
    size_t base = ((size_t)bl*NPAD + n)*HH;
    const float* xr = xbs[nloc];
    #pragma unroll
    for (int j = 0; j < 8; j++) {
        int ch0 = j*64 + lane*2;
        float v0, v1;
        if (j < 2) {
            float a0 = tsbs[ch0], a1 = tsbs[ch0+1];
            #pragma unroll
            for (int k = 0; k < 36; k++) {
                float xv = xr[k];
                a0 += xv * tsw[ch0*37 + k];
                a1 += xv * tsw[(ch0+1)*37 + k];
            }
            v0 = a0; v1 = a1;
        } else if (j < 4) {
            v0 = ldf(mb, n*128 + ch0 - 128, f);
            v1 = ldf(mb, n*128 + ch0 - 127, f);
        } else if (j < 6) {
            v0 = ldf(tide, tidx[bg]*128 + ch0 - 256, f);
            v1 = ldf(tide, tidx[bg]*128 + ch0 - 255, f);
        } else {
            v0 = ldf(diwe, didx[bg]*128 + ch0 - 384, f);
            v1 = ldf(diwe, didx[bg]*128 + ch0 - 383, f);
        }
        unsigned short h0 = bfbits(v0), h1 = bfbits(v1);
        __hip_bfloat16 hb0, hb1;
        *(unsigned short*)&hb0 = h0; *(unsigned short*)&hb1 = h1;
        unsigned short l0 = bfbits(v0 - bf2f(hb0)), l1 = bfbits(v1 - bf2f(hb1));
        *(unsigned*)(Xhi + base + ch0) = (unsigned)h0 | ((unsigned)h1 << 16);
        *(unsigned*)(Xlo + base + ch0) = (unsigned)l0 | ((unsigned)l1 << 16);
    }
}

// ---------------- MFMA GEMM, SWAPPED operands: A=X (rows n), B=W (rows ho) ----------------
// D: row=n (quad*4+r), col=ho (lane&15) -> coalesced epilogue on n-major Y.
// Big gemms: 1D grid 896, decode lin = r + 224*y so ho-siblings share an XCD.
// REGT: 3D grid (7,1,CH); writes regT (b,N,36) + bn2 partials.
template<bool RELU, bool RESID, bool REGT>
__global__ void __launch_bounds__(256)
k_gemm_r13(const __hip_bfloat16* __restrict__ Whi, const __hip_bfloat16* __restrict__ Wlo,
           long Woff, const void* __restrict__ bias, long boff,
           const int* __restrict__ dflag,
           const __hip_bfloat16* __restrict__ Xhi, const __hip_bfloat16* __restrict__ Xlo,
           __hip_bfloat16* __restrict__ Yhi, __hip_bfloat16* __restrict__ Ylo,
           float* __restrict__ regT, float* __restrict__ pb2, int HO, int b0)
{
    __shared__ __align__(16) short sm[4*LREG];   // Whi|Wlo|Xhi|Xlo (32 KB)
    int tid = threadIdx.x;
    int bx, by, bz;
    if constexpr (REGT) {
        bx = blockIdx.x; by = 0; bz = blockIdx.z;
    } else {
        int lin = blockIdx.x;
        by = lin / 224;              // ho-tile: siblings 224 apart -> same XCD
        int r = lin % 224;
        bx = r % 7; bz = r / 7;
    }
    int n0 = bx * 128, ho0 = by * 128;
    int lane = tid & 63, wave = tid >> 6;
    int wm = wave & 1, wn = wave >> 1;       // wm: n-half, wn: ho-half
    int lm = lane & 15, quad = lane >> 4;

    f32x4 acc[4][4];
    #pragma unroll
    for (int i = 0; i < 4; i++)
        #pragma unroll
        for (int j = 0; j < 4; j++) acc[i][j] = (f32x4){0.f, 0.f, 0.f, 0.f};

    const size_t xb0 = (size_t)bz*NPAD*HH;
    int rri[2], nBi[2], kci[2], lofsi[2];
    #pragma unroll
    for (int it = 0; it < 2; it++) {
        int s = it*256 + tid;
        int row = s >> 2; kci[it] = (s & 3) * 8;
        int rr = ho0 + row; rri[it] = (rr >= HO) ? HO - 1 : rr;   // W rows (ho)
        int nB = n0 + row; nBi[it] = (nB >= NN) ? NN - 1 : nB;    // X rows (n)
        lofsi[it] = s * 8;
    }

    for (int k0 = 0; k0 < 512; k0 += 32) {
        #pragma unroll
        for (int it = 0; it < 2; it++) {
            size_t wofs = (size_t)Woff + (size_t)rri[it]*512 + k0 + kci[it];
            size_t xofs = xb0 + (size_t)nBi[it]*HH + k0 + kci[it];
            int lofs = lofsi[it];
            async_copy16(Whi + wofs, &sm[lofs]);
            async_copy16(Wlo + wofs, &sm[LREG + lofs]);
            async_copy16(Xhi + xofs, &sm[2*LREG + lofs]);
            async_copy16(Xlo + xofs, &sm[3*LREG + lofs]);
        }
        __syncthreads();
        bf16x8 ah[4], al[4], bh[4], bl[4];     // a = X frags (n rows), b = W frags (ho rows)
        #pragma unroll
        for (int mi = 0; mi < 4; mi++) {
            int o = (wm*64 + mi*16 + lm)*LSTR + quad*8;
            ah[mi] = *(const bf16x8*)&sm[2*LREG + o];
            al[mi] = *(const bf16x8*)&sm[3*LREG + o];
        }
        #pragma unroll
        for (int ni = 0; ni < 4; ni++) {
            int o = (wn*64 + ni*16 + lm)*LSTR + quad*8;
            bh[ni] = *(const bf16x8*)&sm[o];
            bl[ni] = *(const bf16x8*)&sm[LREG + o];
        }
        #pragma unroll
        for (int mi = 0; mi < 4; mi++)
            #pragma unroll
            for (int ni = 0; ni < 4; ni++) {
                acc[mi][ni] = __builtin_amdgcn_mfma_f32_16x16x32_bf16(ah[mi], bh[ni], acc[mi][ni], 0, 0, 0);
                acc[mi][ni] = __builtin_amdgcn_mfma_f32_16x16x32_bf16(ah[mi], bl[ni], acc[mi][ni], 0, 0, 0);
                acc[mi][ni] = __builtin_amdgcn_mfma_f32_16x16x32_bf16(al[mi], bh[ni], acc[mi][ni], 0, 0, 0);
            }
        __syncthreads();
    }

    int f = *dflag;
    float s0=0,s1=0,s2=0,q0=0,q1=0,q2=0;
    #pragma unroll
    for (int ni = 0; ni < 4; ni++) {
        int ho = ho0 + wn*64 + ni*16 + lm;           // per-lane column
        bool hok = !REGT || (ho < 36);
        float bv = 0.f;
        if (hok) bv = ldf(bias, boff + ho, f);
        int c = REGT ? (ho / 12) : 0;
        #pragma unroll
        for (int mi = 0; mi < 4; mi++) {
            int nr0 = n0 + wm*64 + mi*16 + quad*4;
            #pragma unroll
            for (int r = 0; r < 4; r++) {
                int nr = nr0 + r;
                if (nr >= NN) continue;
                float v = acc[mi][ni][r] + bv;
                if constexpr (REGT) {
                    if (hok) {
                        regT[((size_t)(b0 + bz)*NN + nr)*36 + ho] = v;
                        float v2 = v*v;
                        s0 += (c == 0) ? v : 0.f;  q0 += (c == 0) ? v2 : 0.f;
                        s1 += (c == 1) ? v : 0.f;  q1 += (c == 1) ? v2 : 0.f;
                        s2 += (c == 2) ? v : 0.f;  q2 += (c == 2) ? v2 : 0.f;
                    }
                } else {
                    size_t o = xb0 + (size_t)nr*HH + ho;
                    if constexpr (RESID) v += bf2f(Yhi[o]) + bf2f(Ylo[o]);
                    if constexpr (RELU)  v = fmaxf(v, 0.f);
                    __hip_bfloat16 h = __float2bfloat16(v);
                    Yhi[o] = h;
                    Ylo[o] = __float2bfloat16(v - bf2f(h));
                }
            }
        }
    }
    if constexpr (REGT) {
        float* red = (float*)sm;
        red[0*256 + tid] = s0; red[1*256 + tid] = s1; red[2*256 + tid] = s2;
        red[3*256 + tid] = q0; red[4*256 + tid] = q1; red[5*256 + tid] = q2;
        __syncthreads();
        for (int st = 128; st > 0; st >>= 1) {
            if (tid < st) {
                #pragma unroll
                for (int j = 0; j < 6; j++) red[j*256 + tid] += red[j*256 + tid + st];
            }
            __syncthreads();
        }
        if (tid < 6) pb2[((b0 + bz)*7 + bx)*6 + tid] = red[tid*256];
    }
}

// ---------------- xpre = bn2(regT) + conv(bn1(in)); bn3 partials ----------------
__global__ void __launch_bounds__(256)
k_xpre_r13(const float* __restrict__ regT, const void* __restrict__ in,
           const void* __restrict__ convW, const void* __restrict__ convb,
           const int* __restrict__ dflag, const float* __restrict__ st1,
           const float* __restrict__ st2, float* __restrict__ pb3,
           float* __restrict__ xpre)
{
    int f = *dflag;
    float m1[3], r1[3], m2[3], r2[3], cw[9], cb[3];
    #pragma unroll
    for (int c = 0; c < 3; c++) {
        float m = st1[c] * (1.0f/CNT_PER_C);
        float v = st1[3+c] * (1.0f/CNT_PER_C) - m*m;
        m1[c] = m; r1[c] = 1.0f / sqrtf(v + 1e-5f);
        float mm = st2[c] * (1.0f/CNT_PER_C);
        float vv = st2[3+c] * (1.0f/CNT_PER_C) - mm*mm;
        m2[c] = mm; r2[c] = 1.0f / sqrtf(vv + 1e-5f);
        cb[c] = ldf(convb, c, f);
    }
    #pragma unroll
    for (int j = 0; j < 9; j++) cw[j] = ldf(convW, j, f);
    float s0=0,s1=0,s2=0,q0=0,q1=0,q2=0;
    for (int i = blockIdx.x*256 + threadIdx.x; i < TOT_X; i += 1024*256) {
        int b = i / 31788, r1_ = i % 31788;
        int c = r1_ / NL, r2_ = r1_ % NL;
        int n = r2_ / 12, l = r2_ % 12;
        float hidv = (regT[((size_t)b*NN + n)*36 + c*12 + l] - m2[c]) * r2[c];
        float cx = cb[c];
        #pragma unroll
        for (int cc = 0; cc < 3; cc++) {
            float xbv = (ldf(in, ((long)(b*3 + cc)*NN + n)*12 + l, f) - m1[cc]) * r1[cc];
            cx += cw[c*3 + cc] * xbv;
        }
        float v = hidv + cx;
        xpre[i] = v;
        float v2 = v*v;
        s0 += (c == 0) ? v : 0.f;  q0 += (c == 0) ? v2 : 0.f;
        s1 += (c == 1) ? v : 0.f;  q1 += (c == 1) ? v2 : 0.f;
        s2 += (c == 2) ? v : 0.f;  q2 += (c == 2) ? v2 : 0.f;
    }
    __shared__ float red[6][256];
    int t = threadIdx.x;
    red[0][t] = s0; red[1][t] = s1; red[2][t] = s2;
    red[3][t] = q0; red[4][t] = q1; red[5][t] = q2;
    __syncthreads();
    for (int st_ = 128; st_ > 0; st_ >>= 1) {
        if (t < st_) {
            #pragma unroll
            for (int j = 0; j < 6; j++) red[j][t] += red[j][t+st_];
        }
        __syncthreads();
    }
    if (t < 6) pb3[blockIdx.x*6 + t] = red[t][0];
}

// ---------------- tail per (b,n) ----------------
__global__ void __launch_bounds__(64)
k_tail_r13(const float* __restrict__ xpre, const float* __restrict__ st3,
           const float* __restrict__ phi, const float* __restrict__ topval,
           const int* __restrict__ topidx, const float* __restrict__ wc,
           const void* __restrict__ wie, const void* __restrict__ mixp,
           const int* __restrict__ dflag, float* __restrict__ out)
{
    int f = *dflag;
    int n = blockIdx.x, b = blockIdx.y, t = threadIdx.x;
    __shared__ float xe[3][10][12], mn[3][10], phis[24], ws[10];
    __shared__ float pm[3][10][12], pred[3][12];
    float m3[3], rs3[3];
    #pragma unroll
    for (int c = 0; c < 3; c++) {
        float m = st3[c] * (1.0f/CNT_PER_C);
        float v = st3[3+c] * (1.0f/CNT_PER_C) - m*m;
        m3[c] = m; rs3[c] = 1.0f / sqrtf(v + 1e-5f);
    }
    if (t < 24) phis[t] = phi[b*24 + t];
    if (t < 10) ws[t] = (t == 0 ? 1.0f : topval[n*9 + t - 1]) * ldf(wie, t, f);
    for (int i = t; i < 360; i += 64) {
        int c = i / 120, m = (i / 12) % 10, l = i % 12;
        int nn2 = (m == 0) ? n : topidx[n*9 + m - 1];
        xe[c][m][l] = (xpre[((size_t)(b*3 + c)*NN + nn2)*12 + l] - m3[c]) * rs3[c];
    }
    __syncthreads();
    if (t < 30) {
        int c = t / 10, m = t % 10;
        float s = 0.f;
        #pragma unroll
        for (int l = 0; l < 12; l++) s += xe[c][m][l];
        mn[c][m] = s * (1.0f/12.0f);
    }
    __syncthreads();
    float mix = ldf(mixp, 0, f);
    for (int pr = t; pr < 120; pr += 64) {
        int m = pr / 12, p = pr % 12;
        float y[3], sc[12], mx = -3.4e38f;
        #pragma unroll
        for (int c = 0; c < 3; c++) y[c] = phis[12+p] + mix*mn[c][m];
        #pragma unroll
        for (int l = 0; l < 12; l++) {
            float v = 0.f;
            #pragma unroll
            for (int c = 0; c < 3; c++) v += y[c] * (phis[l] + mix*mn[c][m]);
            sc[l] = v * (1.0f/36.0f); mx = fmaxf(mx, sc[l]);
        }
        float den = 0.f;
        #pragma unroll
        for (int l = 0; l < 12; l++) { float e = expf(sc[l] - mx); sc[l] = e; den += e; }
        float inv = 1.0f/den;
        float p0 = 0.f, p1 = 0.f, p2 = 0.f;
        #pragma unroll
        for (int l = 0; l < 12; l++) {
            float a = sc[l]*inv;
            p0 += a*xe[0][m][l]; p1 += a*xe[1][m][l]; p2 += a*xe[2][m][l];
        }
        pm[0][m][p] = p0; pm[1][m][p] = p1; pm[2][m][p] = p2;
    }
    __syncthreads();
    if (t < 36) {
        int c = t/12, p = t%12;
        float s = 0.f;
        #pragma unroll
        for (int m = 0; m < 10; m++) s += pm[c][m][p]*ws[m];
        pred[c][p] = s;
    }
    __syncthreads();
    if (t < 36) {
        int o = t/12, p = t%12;
        float o1 = wc[9+o]  + wc[o*3+0]*pred[0][p] + wc[o*3+1]*pred[1][p] + wc[o*3+2]*pred[2][p];
        float o2 = wc[21+o] + wc[12+o*3+0]*pred[0][p] + wc[12+o*3+1]*pred[1][p] + wc[12+o*3+2]*pred[2][p];
        out[((size_t)(b*3 + o)*NN + n)*12 + p] = o1 / (1.0f + expf(-o2));
    }
}

// ---------------------------------------------------------------------------
extern "C" void kernel_launch(void* const* d_in, const int* in_sizes, int n_in,
                              void* d_out, int out_size, void* d_ws, size_t ws_size,
                              hipStream_t stream)
{
    (void)in_sizes; (void)n_in;
    char* w = (char*)d_ws;
    auto alloc = [&](size_t bytes) { char* p = w; w += (bytes + 255) & ~(size_t)255; return p; };

    float* regT   = (float*)alloc((size_t)TOT_X*4);
    float* xpre   = (float*)alloc((size_t)TOT_X*4);
    __hip_bfloat16* Whi1 = (__hip_bfloat16*)alloc(786432*2);
    __hip_bfloat16* Wlo1 = (__hip_bfloat16*)alloc(786432*2);
    __hip_bfloat16* Whi2 = (__hip_bfloat16*)alloc(786432*2);
    __hip_bfloat16* Wlo2 = (__hip_bfloat16*)alloc(786432*2);
    __hip_bfloat16* rhi  = (__hip_bfloat16*)alloc(18432*2);
    __hip_bfloat16* rlo  = (__hip_bfloat16*)alloc(18432*2);
    float* e1     = (float*)alloc(113024*4);
    float* e2t    = (float*)alloc(113024*4);
    float* phi    = (float*)alloc(768*4);
    float* topval = (float*)alloc(7947*4);
    int*   topidx = (int*)alloc(7947*4);
    int*   tidx   = (int*)alloc(32*4);
    int*   didx   = (int*)alloc(32*4);
    float* stats  = (float*)alloc(18*4);
    float* wc     = (float*)alloc(24*4);
    int*   dflag  = (int*)alloc(4);
    float* pb1    = (float*)alloc(512*6*4);
    float* pb2    = (float*)alloc(224*6*4);
    float* pb3    = (float*)alloc(1024*6*4);
    size_t fixedEnd = (size_t)(w - (char*)d_ws);

    const size_t XB = (size_t)NPAD*HH*2;
    int CH = 0;
    for (int c = 32; c >= 1; c >>= 1) {
        if (fixedEnd + 4*(size_t)c*XB + 4096 <= ws_size) { CH = c; break; }
    }
    if (CH == 0) {
        k_sent_r13<<<(out_size + 255)/256, 256, 0, stream>>>((float*)d_out, out_size);
        return;
    }
    char* regionB = w;
    __hip_bfloat16* Xahi = (__hip_bfloat16*)regionB;
    __hip_bfloat16* Xalo = (__hip_bfloat16*)(regionB + (size_t)CH*XB);
    __hip_bfloat16* Xbhi = (__hip_bfloat16*)(regionB + 2*(size_t)CH*XB);
    __hip_bfloat16* Xblo = (__hip_bfloat16*)(regionB + 3*(size_t)CH*XB);

    k_probe_r13<<<1, 256, 0, stream>>>((const unsigned short*)d_in[0], dflag);
    k_prep_r13<<<1, 256, 0, stream>>>(d_in[2], d_in[3], d_in[19], d_in[20], d_in[21], d_in[22],
                                      d_in[25], d_in[26], d_in[27], d_in[28], d_in[29], d_in[30],
                                      dflag, tidx, didx, phi, wc);
    k_wsplit_r13<<<1024, 256, 0, stream>>>(d_in[13], dflag, 786432, Whi1, Wlo1);
    k_wsplit_r13<<<1024, 256, 0, stream>>>(d_in[15], dflag, 786432, Whi2, Wlo2);
    k_wsplit_r13<<<72,   256, 0, stream>>>(d_in[17], dflag, 18432, rhi, rlo);

    k_e_r13<<<883, 256, 0, stream>>>(d_in[4], d_in[5], d_in[6], dflag, e1, e2t);
    k_graph_r13<<<883, 256, 0, stream>>>(e1, e2t, topval, topidx);
    k_bn1_r13<<<512, 256, 0, stream>>>(d_in[0], dflag, pb1);
    k_fin_r13<<<1, 256, 0, stream>>>(pb1, 512, stats);

    for (int b0 = 0; b0 < BB; b0 += CH) {
        k_hid_r13<<<dim3(111, CH), 256, 0, stream>>>(d_in[0], d_in[4], d_in[7], d_in[8],
                                                     d_in[9], d_in[10], tidx, didx, dflag,
                                                     stats, b0, Xahi, Xalo);
        int grid1 = 224 * 4;   // assumes CH=32 chunk; generalize below
        int nblk = 7 * CH;     // blocks per ho-tile
        grid1 = nblk * 4;
        for (int i = 0; i < 3; i++) {
            k_gemm_r13<true, false, false><<<grid1, 256, 0, stream>>>(
                Whi1, Wlo1, (long)i*HH*HH, d_in[14], (long)i*HH, dflag,
                Xahi, Xalo, Xbhi, Xblo, (float*)nullptr, (float*)nullptr, HH, b0);
            k_gemm_r13<false, true, false><<<grid1, 256, 0, stream>>>(
                Whi2, Wlo2, (long)i*HH*HH, d_in[16], (long)i*HH, dflag,
                Xbhi, Xblo, Xahi, Xalo, (float*)nullptr, (float*)nullptr, HH, b0);
        }
        k_gemm_r13<false, false, true><<<dim3(7, 1, CH), 256, 0, stream>>>(
            rhi, rlo, 0, d_in[18], 0, dflag,
            Xahi, Xalo, (__hip_bfloat16*)nullptr, (__hip_bfloat16*)nullptr,
            regT, pb2, 36, b0);
    }
    k_fin_r13<<<1, 256, 0, stream>>>(pb2, 224, stats + 6);

    k_xpre_r13<<<1024, 256, 0, stream>>>(regT, d_in[0], d_in[11], d_in[12], dflag,
                                         stats, stats + 6, pb3, xpre);
    k_fin_r13<<<1, 256, 0, stream>>>(pb3, 1024, stats + 12);

    k_tail_r13<<<dim3(NN, BB), 64, 0, stream>>>(xpre, stats + 12, phi, topval, topidx, wc,
                                                d_in[24], d_in[23], dflag, (float*)d_out);
}

// Round 14
// 806.557 us; speedup vs baseline: 1.1100x; 1.1100x over previous
//
#include <hip/hip_runtime.h>
#include <hip/hip_bf16.h>

// ---------------------------------------------------------------------------
// STD2Vformer forward, MI355X. Round 14 (R12 @838us baseline; R13 swap regressed):
//  - R12 core (grid (7,4,CH), A=W B=X, async staging) restored verbatim
//  - big-gemm epilogue: LDS-transposed 2-pass store -> 64B-contiguous int4
//    writes/resid-reads on n-major Y (R13's WRITE win w/o its fetch/scalar loss)
// ---------------------------------------------------------------------------

#define NN 883
#define NPAD 896
#define BB 32
#define HH 512
#define NL 10596            // N*L
#define CNT_PER_C 339072.0f // B*N*L
#define TOT_X 1017216       // B*C*N*L
#define LSTR 32             // LDS row stride in shorts (64B)
#define LREG 4096           // shorts per LDS operand region (128*LSTR)

typedef __attribute__((ext_vector_type(8))) short bf16x8;
typedef __attribute__((ext_vector_type(4))) float f32x4;

static __device__ __forceinline__ float bf2f(__hip_bfloat16 v) { return __bfloat162float(v); }
static __device__ __forceinline__ float ldf(const void* p, long i, int f) {
    return f ? ((const float*)p)[i] : bf2f(((const __hip_bfloat16*)p)[i]);
}
static __device__ __forceinline__ unsigned short bfbits(float v) {
    __hip_bfloat16 h = __float2bfloat16(v);
    return *(unsigned short*)&h;
}
static __device__ __forceinline__ void async_copy16(const void* g, void* l) {
    __builtin_amdgcn_global_load_lds((const __attribute__((address_space(1))) void*)g,
                                     (__attribute__((address_space(3))) void*)l, 16, 0, 0);
}

// ---------------- sentinel ----------------
__global__ void k_sent_r14(float* __restrict__ out, int n)
{
    int i = blockIdx.x*256 + threadIdx.x;
    if (i < n) out[i] = 1000.0f;
}

// ---------------- input dtype probe ----------------
__global__ void k_probe_r14(const unsigned short* __restrict__ u, int* __restrict__ flag)
{
    int t = threadIdx.x, cnt = 0;
    for (int i = t; i < 4096; i += 256) {
        int e = (u[i] >> 7) & 0xFF;
        cnt += (e >= 0xC0);
    }
    __shared__ int r[256];
    r[t] = cnt; __syncthreads();
    for (int s = 128; s > 0; s >>= 1) { if (t < s) r[t] += r[t+s]; __syncthreads(); }
    if (t == 0) *flag = (r[0] > 8) ? 1 : 0;
}

// ---------------- finalize: sum P rows of 6 partials ----------------
__global__ void k_fin_r14(const float* __restrict__ pb, int P, float* __restrict__ out)
{
    int t = threadIdx.x;
    float s[6] = {0,0,0,0,0,0};
    for (int r = t; r < P; r += 256)
        #pragma unroll
        for (int j = 0; j < 6; j++) s[j] += pb[r*6 + j];
    __shared__ float red[6][256];
    #pragma unroll
    for (int j = 0; j < 6; j++) red[j][t] = s[j];
    __syncthreads();
    for (int st = 128; st > 0; st >>= 1) {
        if (t < st) {
            #pragma unroll
            for (int j = 0; j < 6; j++) red[j][t] += red[j][t+st];
        }
        __syncthreads();
    }
    if (t < 6) out[t] = red[t][0];
}

// ---------------- weight hi/lo split ----------------
__global__ void k_wsplit_r14(const void* __restrict__ src, const int* __restrict__ dflag,
                             int n, __hip_bfloat16* __restrict__ hi,
                             __hip_bfloat16* __restrict__ lo)
{
    int f = *dflag;
    for (int i = blockIdx.x*256 + threadIdx.x; i < n; i += gridDim.x*256) {
        float v = ldf(src, i, f);
        __hip_bfloat16 h = __float2bfloat16(v);
        hi[i] = h;
        lo[i] = __float2bfloat16(v - bf2f(h));
    }
}

// ---------------- prep ----------------
__global__ void k_prep_r14(const void* __restrict__ seqs, const void* __restrict__ tgts,
                           const void* __restrict__ w0, const void* __restrict__ b0,
                           const void* __restrict__ d2vW, const void* __restrict__ d2vb,
                           const void* __restrict__ fusW, const void* __restrict__ fusb,
                           const void* __restrict__ g1W, const void* __restrict__ g1b,
                           const void* __restrict__ g2W, const void* __restrict__ g2b,
                           const int* __restrict__ dflag,
                           int* __restrict__ tidx, int* __restrict__ didx,
                           float* __restrict__ phi, float* __restrict__ wc)
{
    int f = *dflag, t = threadIdx.x;
    if (t < 32) {
        int b = t;
        float h  = (ldf(seqs, (b*5+3)*12 + 11, f) + 0.5f) * 23.0f;
        float mi = (ldf(seqs, (b*5+4)*12 + 11, f) + 0.5f) * 59.0f;
        int ti = (int)((h * 60.0f + mi) / 5.0f);
        tidx[b] = ti < 0 ? 0 : (ti > 287 ? 287 : ti);
        int di = (int)((ldf(seqs, (b*5+2)*12 + 11, f) + 0.5f) * 6.0f);
        didx[b] = di < 0 ? 0 : (di > 6 ? 6 : di);
    }
    for (int i = t; i < 768; i += 256) {
        int b = i / 24, tt = i % 24;
        float tau[5];
        #pragma unroll
        for (int d = 0; d < 5; d++)
            tau[d] = (tt < 12) ? ldf(seqs, (b*5+d)*12 + tt, f)
                               : ldf(tgts, (b*5+d)*12 + tt - 12, f);
        float s = ldf(b0, 0, f);
        #pragma unroll
        for (int d = 0; d < 5; d++) s += tau[d] * ldf(w0, d, f);
        for (int k = 0; k < 16; k++) {
            float arg = ldf(d2vb, k, f);
            #pragma unroll
            for (int d = 0; d < 5; d++) arg += tau[d] * ldf(d2vW, k*5 + d, f);
            s += sinf(arg);
        }
        phi[i] = s;
    }
    if (t < 24) {
        if (t < 9) {
            int o = t / 3, c = t % 3; float s = 0.f;
            for (int d = 0; d < 128; d++) s += ldf(fusW, c*128+d, f) * ldf(g1W, d*3+o, f);
            wc[t] = s;
        } else if (t < 12) {
            int o = t - 9; float s = ldf(g1b, o, f);
            for (int d = 0; d < 128; d++) s += ldf(fusb, d, f) * ldf(g1W, d*3+o, f);
            wc[9 + o] = s;
        } else if (t < 21) {
            int j = t - 12; int o = j / 3, c = j % 3; float s = 0.f;
            for (int d = 0; d < 128; d++) s += ldf(fusW, c*128+d, f) * ldf(g2W, d*3+o, f);
            wc[12 + j] = s;
        } else {
            int o = t - 21; float s = ldf(g2b, o, f);
            for (int d = 0; d < 128; d++) s += ldf(fusb, d, f) * ldf(g2W, d*3+o, f);
            wc[21 + o] = s;
        }
    }
}

// ---------------- e1 (n-major) and e2t (d-major) ----------------
__global__ void k_e_r14(const void* __restrict__ mb, const void* __restrict__ We1,
                        const void* __restrict__ We2, const int* __restrict__ dflag,
                        float* __restrict__ e1, float* __restrict__ e2t)
{
    int f = *dflag;
    int idx = blockIdx.x*256 + threadIdx.x;
    int which = idx >= 113024;
    int j = which ? idx - 113024 : idx;
    int d = j & 127, n = j >> 7;
    const void* W = which ? We2 : We1;
    float s = 0.f;
    for (int k = 0; k < 128; k++)
        s += ldf(mb, n*128 + k, f) * ldf(W, k*128 + d, f);
    if (which) e2t[d*NN + n] = s;
    else       e1[j] = s;
}

// ---- fused graph ----
__global__ void __launch_bounds__(256)
k_graph_r14(const float* __restrict__ e1, const float* __restrict__ e2t,
            float* __restrict__ topval, int* __restrict__ topidx)
{
    int n = blockIdx.x, t = threadIdx.x;
    __shared__ float e1s[128];
    __shared__ float arow[NN];
    __shared__ float red[256];
    __shared__ int redi[256];
    if (t < 128) e1s[t] = e1[n*128 + t];
    __syncthreads();
    for (int m = t; m < NN; m += 256) {
        float acc = 0.f;
        #pragma unroll 8
        for (int k = 0; k < 128; k++) acc += e1s[k] * e2t[k*NN + m];
        arow[m] = acc;
    }
    __syncthreads();
    float s = 0.f;
    for (int m = t; m < NN; m += 256) s += arow[m];
    red[t] = s; __syncthreads();
    for (int st = 128; st > 0; st >>= 1) { if (t < st) red[t] += red[t+st]; __syncthreads(); }
    float mean = red[0] / 883.0f; __syncthreads();
    float ss = 0.f;
    for (int m = t; m < NN; m += 256) { float d = arow[m] - mean; ss += d*d; }
    red[t] = ss; __syncthreads();
    for (int st = 128; st > 0; st >>= 1) { if (t < st) red[t] += red[t+st]; __syncthreads(); }
    float rstd = 1.0f / sqrtf(red[0] / 882.0f); __syncthreads();
    for (int m = t; m < NN; m += 256) {
        float z = (arow[m] - mean) * rstd;
        z = fmaxf(z, 0.f);
        if (m == n) z -= 1e6f;
        arow[m] = z;
    }
    __syncthreads();
    float mx = -3.4e38f;
    for (int m = t; m < NN; m += 256) mx = fmaxf(mx, arow[m]);
    red[t] = mx; __syncthreads();
    for (int st = 128; st > 0; st >>= 1) { if (t < st) red[t] = fmaxf(red[t], red[t+st]); __syncthreads(); }
    float M = red[0]; __syncthreads();
    float ds = 0.f;
    for (int m = t; m < NN; m += 256) { float e = expf(arow[m] - M); arow[m] = e; ds += e; }
    red[t] = ds; __syncthreads();
    for (int st = 128; st > 0; st >>= 1) { if (t < st) red[t] += red[t+st]; __syncthreads(); }
    float inv = 1.0f / red[0]; __syncthreads();
    for (int m = t; m < NN; m += 256) arow[m] *= inv;
    __syncthreads();
    for (int j = 0; j < 9; j++) {
        float bv = -1.f; int bi = 0;
        for (int m = t; m < NN; m += 256) { float v = arow[m]; if (v > bv) { bv = v; bi = m; } }
        red[t] = bv; redi[t] = bi; __syncthreads();
        for (int st = 128; st > 0; st >>= 1) {
            if (t < st) {
                float ov = red[t+st]; int oi = redi[t+st];
                if (ov > red[t] || (ov == red[t] && oi < redi[t])) { red[t] = ov; redi[t] = oi; }
            }
            __syncthreads();
        }
        if (t == 0) {
            topval[n*9 + j] = red[0];
            topidx[n*9 + j] = redi[0];
            arow[redi[0]] = -1.f;
        }
        __syncthreads();
    }
}

// ---------------- bn1 stats -> partials ----------------
__global__ void k_bn1_r14(const void* __restrict__ x, const int* __restrict__ dflag,
                          float* __restrict__ pb)
{
    int f = *dflag;
    float s[3] = {0,0,0}, q[3] = {0,0,0};
    for (int i = blockIdx.x*256 + threadIdx.x; i < TOT_X; i += 512*256) {
        int c = (i / NL) % 3;
        float v = ldf(x, i, f);
        s[c] += v; q[c] += v*v;
    }
    __shared__ float red[6][256];
    int t = threadIdx.x;
    #pragma unroll
    for (int j = 0; j < 3; j++) { red[j][t] = s[j]; red[3+j][t] = q[j]; }
    __syncthreads();
    for (int st_ = 128; st_ > 0; st_ >>= 1) {
        if (t < st_) {
            #pragma unroll
            for (int j = 0; j < 6; j++) red[j][t] += red[j][t+st_];
        }
        __syncthreads();
    }
    if (t < 6) pb[blockIdx.x*6 + t] = red[t][0];
}

// ---------------- build hidden (hi,lo); 8 nodes/block ----------------
__global__ void __launch_bounds__(256)
k_hid_r14(const void* __restrict__ in, const void* __restrict__ mb,
          const void* __restrict__ tide, const void* __restrict__ diwe,
          const void* __restrict__ tsW, const void* __restrict__ tsb,
          const int* __restrict__ tidx, const int* __restrict__ didx,
          const int* __restrict__ dflag, const float* __restrict__ st1,
          int b0, __hip_bfloat16* __restrict__ Xhi, __hip_bfloat16* __restrict__ Xlo)
{
    int f = *dflag;
    int bl = blockIdx.y, bg = b0 + bl, t = threadIdx.x;
    int n0 = blockIdx.x * 8;
    __shared__ float tsw[128*37];
    __shared__ float tsbs[128];
    __shared__ float xbs[8][36];
    float m1[3], r1v[3];
    #pragma unroll
    for (int c = 0; c < 3; c++) {
        float m = st1[c] * (1.0f/CNT_PER_C);
        float v = st1[3+c] * (1.0f/CNT_PER_C) - m*m;
        m1[c] = m; r1v[c] = 1.0f / sqrtf(v + 1e-5f);
    }
    for (int i = t; i < 4608; i += 256)
        tsw[(i/36)*37 + (i%36)] = ldf(tsW, i, f);
    if (t < 128) tsbs[t] = ldf(tsb, t, f);
    for (int i = t; i < 288; i += 256) {
        int nl = i / 36, k = i % 36;
        int c = k / 12, l = k % 12;
        int n = n0 + nl; if (n >= NN) n = NN - 1;
        xbs[nl][k] = (ldf(in, ((long)(bg*3 + c)*NN + n)*12 + l, f) - m1[c]) * r1v[c];
    }
    __syncthreads();
    int nloc = t >> 5, lane = t & 31;
    int n = n0 + nloc;
    if (n >= NN) return;
    size_t base = ((size_t)bl*NPAD + n)*HH;
    const float* xr = xbs[nloc];
    #pragma unroll
    for (int j = 0; j < 8; j++) {
        int ch0 = j*64 + lane*2;
        float v0, v1;
        if (j < 2) {
            float a0 = tsbs[ch0], a1 = tsbs[ch0+1];
            #pragma unroll
            for (int k = 0; k < 36; k++) {
                float xv = xr[k];
                a0 += xv * tsw[ch0*37 + k];
                a1 += xv * tsw[(ch0+1)*37 + k];
            }
            v0 = a0; v1 = a1;
        } else if (j < 4) {
            v0 = ldf(mb, n*128 + ch0 - 128, f);
            v1 = ldf(mb, n*128 + ch0 - 127, f);
        } else if (j < 6) {
            v0 = ldf(tide, tidx[bg]*128 + ch0 - 256, f);
            v1 = ldf(tide, tidx[bg]*128 + ch0 - 255, f);
        } else {
            v0 = ldf(diwe, didx[bg]*128 + ch0 - 384, f);
            v1 = ldf(diwe, didx[bg]*128 + ch0 - 383, f);
        }
        unsigned short h0 = bfbits(v0), h1 = bfbits(v1);
        __hip_bfloat16 hb0, hb1;
        *(unsigned short*)&hb0 = h0; *(unsigned short*)&hb1 = h1;
        unsigned short l0 = bfbits(v0 - bf2f(hb0)), l1 = bfbits(v1 - bf2f(hb1));
        *(unsigned*)(Xhi + base + ch0) = (unsigned)h0 | ((unsigned)h1 << 16);
        *(unsigned*)(Xlo + base + ch0) = (unsigned)l0 | ((unsigned)l1 << 16);
    }
}

// ---------------- MFMA GEMM (R12 core): A=W rows ho, B=X rows n ----------------
// Big gemms: epilogue via LDS transpose -> coalesced int4 writes on n-major Y.
// REGT: R12 epilogue (regT + bn2 partials).
template<bool RELU, bool RESID, bool REGT>
__global__ void __launch_bounds__(256)
k_gemm_r14(const __hip_bfloat16* __restrict__ Whi, const __hip_bfloat16* __restrict__ Wlo,
           long Woff, const void* __restrict__ bias, long boff,
           const int* __restrict__ dflag,
           const __hip_bfloat16* __restrict__ Xhi, const __hip_bfloat16* __restrict__ Xlo,
           __hip_bfloat16* __restrict__ Yhi, __hip_bfloat16* __restrict__ Ylo,
           float* __restrict__ regT, float* __restrict__ pb2, int HO, int b0)
{
    __shared__ __align__(16) char smbuf[34048];   // max(32768 staging, 64*133*4 transpose)
    short* sm = (short*)smbuf;
    float* smT = (float*)smbuf;
    int tid = threadIdx.x, bz = blockIdx.z;
    int n0 = blockIdx.x * 128, ho0 = blockIdx.y * 128;
    int lane = tid & 63, wave = tid >> 6;
    int wm = wave & 1, wn = wave >> 1;
    int lm = lane & 15, quad = lane >> 4;

    f32x4 acc[4][4];
    #pragma unroll
    for (int i = 0; i < 4; i++)
        #pragma unroll
        for (int j = 0; j < 4; j++) acc[i][j] = (f32x4){0.f, 0.f, 0.f, 0.f};

    const size_t xb0 = (size_t)bz*NPAD*HH;
    int rri[2], nBi[2], kci[2], lofsi[2];
    #pragma unroll
    for (int it = 0; it < 2; it++) {
        int s = it*256 + tid;
        int row = s >> 2; kci[it] = (s & 3) * 8;
        int rr = ho0 + row; rri[it] = (rr >= HO) ? HO - 1 : rr;
        int nB = n0 + row; nBi[it] = (nB >= NN) ? NN - 1 : nB;
        lofsi[it] = s * 8;
    }

    for (int k0 = 0; k0 < 512; k0 += 32) {
        #pragma unroll
        for (int it = 0; it < 2; it++) {
            size_t wofs = (size_t)Woff + (size_t)rri[it]*512 + k0 + kci[it];
            size_t xofs = xb0 + (size_t)nBi[it]*HH + k0 + kci[it];
            int lofs = lofsi[it];
            async_copy16(Whi + wofs, &sm[lofs]);
            async_copy16(Wlo + wofs, &sm[LREG + lofs]);
            async_copy16(Xhi + xofs, &sm[2*LREG + lofs]);
            async_copy16(Xlo + xofs, &sm[3*LREG + lofs]);
        }
        __syncthreads();
        bf16x8 ah[4], al[4], bh[4], bl[4];
        #pragma unroll
        for (int mi = 0; mi < 4; mi++) {
            int o = (wm*64 + mi*16 + lm)*LSTR + quad*8;
            ah[mi] = *(const bf16x8*)&sm[o];
            al[mi] = *(const bf16x8*)&sm[LREG + o];
        }
        #pragma unroll
        for (int ni = 0; ni < 4; ni++) {
            int o = (wn*64 + ni*16 + lm)*LSTR + quad*8;
            bh[ni] = *(const bf16x8*)&sm[2*LREG + o];
            bl[ni] = *(const bf16x8*)&sm[3*LREG + o];
        }
        #pragma unroll
        for (int mi = 0; mi < 4; mi++)
            #pragma unroll
            for (int ni = 0; ni < 4; ni++) {
                acc[mi][ni] = __builtin_amdgcn_mfma_f32_16x16x32_bf16(ah[mi], bh[ni], acc[mi][ni], 0, 0, 0);
                acc[mi][ni] = __builtin_amdgcn_mfma_f32_16x16x32_bf16(ah[mi], bl[ni], acc[mi][ni], 0, 0, 0);
                acc[mi][ni] = __builtin_amdgcn_mfma_f32_16x16x32_bf16(al[mi], bh[ni], acc[mi][ni], 0, 0, 0);
            }
        __syncthreads();
    }

    int f = *dflag;
    if constexpr (REGT) {
        // R12 epilogue: regT (b,N,36) + bn2 partials
        float s0=0,s1=0,s2=0,q0=0,q1=0,q2=0;
        #pragma unroll
        for (int mi = 0; mi < 4; mi++) {
            int hor = ho0 + wm*64 + mi*16 + quad*4;
            float bv[4];
            #pragma unroll
            for (int r = 0; r < 4; r++) {
                int h = hor + r; if (h >= HO) h = HO - 1;
                bv[r] = ldf(bias, boff + h, f);
            }
            #pragma unroll
            for (int ni = 0; ni < 4; ni++) {
                int nc = n0 + wn*64 + ni*16 + lm;
                if (nc >= NN) continue;
                if (hor <= 32) {
                    int c = hor / 12;
                    float4 v4;
                    v4.x = acc[mi][ni][0] + bv[0];
                    v4.y = acc[mi][ni][1] + bv[1];
                    v4.z = acc[mi][ni][2] + bv[2];
                    v4.w = acc[mi][ni][3] + bv[3];
                    *(float4*)(regT + ((size_t)(b0 + bz)*NN + nc)*36 + hor) = v4;
                    float sx = v4.x + v4.y + v4.z + v4.w;
                    float qx = v4.x*v4.x + v4.y*v4.y + v4.z*v4.z + v4.w*v4.w;
                    s0 += (c == 0) ? sx : 0.f;  q0 += (c == 0) ? qx : 0.f;
                    s1 += (c == 1) ? sx : 0.f;  q1 += (c == 1) ? qx : 0.f;
                    s2 += (c == 2) ? sx : 0.f;  q2 += (c == 2) ? qx : 0.f;
                }
            }
        }
        __syncthreads();
        float* red = (float*)smbuf;
        red[0*256 + tid] = s0; red[1*256 + tid] = s1; red[2*256 + tid] = s2;
        red[3*256 + tid] = q0; red[4*256 + tid] = q1; red[5*256 + tid] = q2;
        __syncthreads();
        for (int st = 128; st > 0; st >>= 1) {
            if (tid < st) {
                #pragma unroll
                for (int j = 0; j < 6; j++) red[j*256 + tid] += red[j*256 + tid + st];
            }
            __syncthreads();
        }
        if (tid < 6) pb2[((b0 + bz)*7 + blockIdx.x)*6 + tid] = red[tid*256];
    } else {
        // LDS-transposed 2-pass epilogue: pass p covers n-local [p*64, p*64+64)
        float bvl[4][4];   // bias per (mi, r): depends on ho only
        #pragma unroll
        for (int mi = 0; mi < 4; mi++) {
            int hor = ho0 + wm*64 + mi*16 + quad*4;
            #pragma unroll
            for (int r = 0; r < 4; r++) bvl[mi][r] = ldf(bias, boff + hor + r, f);
        }
        #pragma unroll
        for (int p = 0; p < 2; p++) {
            if (wn == p) {
                #pragma unroll
                for (int mi = 0; mi < 4; mi++) {
                    int ho = wm*64 + mi*16 + quad*4;     // 0..127 (block-local)
                    #pragma unroll
                    for (int ni = 0; ni < 4; ni++) {
                        int nl = ni*16 + lm;             // 0..63 within half
                        #pragma unroll
                        for (int r = 0; r < 4; r++)
                            smT[nl*133 + ho + r] = acc[mi][ni][r] + bvl[mi][r];
                    }
                }
            }
            __syncthreads();
            // store: 256 threads, 64 rows x 128 ho; thread -> row=tid>>2, 32-ho seg
            {
                int row = tid >> 2, seg = tid & 3;
                int nr = n0 + p*64 + row;                 // may be pad row (<NPAD): safe
                int hob = seg * 32;
                size_t o = xb0 + (size_t)nr*HH + ho0 + hob;
                unsigned short hi16[32], lo16[32];
                if constexpr (RESID) {
                    int4 rh[4], rl[4];
                    #pragma unroll
                    for (int v = 0; v < 4; v++) {
                        rh[v] = *(const int4*)(Yhi + o + v*8);
                        rl[v] = *(const int4*)(Ylo + o + v*8);
                    }
                    const unsigned short* rhp = (const unsigned short*)rh;
                    const unsigned short* rlp = (const unsigned short*)rl;
                    #pragma unroll
                    for (int j = 0; j < 32; j++) {
                        float v = smT[row*133 + hob + j];
                        __hip_bfloat16 hb, lb;
                        *(unsigned short*)&hb = rhp[j];
                        *(unsigned short*)&lb = rlp[j];
                        v += bf2f(hb) + bf2f(lb);
                        if constexpr (RELU) v = fmaxf(v, 0.f);
                        unsigned short h = bfbits(v);
                        __hip_bfloat16 hh; *(unsigned short*)&hh = h;
                        hi16[j] = h;
                        lo16[j] = bfbits(v - bf2f(hh));
                    }
                } else {
                    #pragma unroll
                    for (int j = 0; j < 32; j++) {
                        float v = smT[row*133 + hob + j];
                        if constexpr (RELU) v = fmaxf(v, 0.f);
                        unsigned short h = bfbits(v);
                        __hip_bfloat16 hh; *(unsigned short*)&hh = h;
                        hi16[j] = h;
                        lo16[j] = bfbits(v - bf2f(hh));
                    }
                }
                #pragma unroll
                for (int v = 0; v < 4; v++) {
                    *(int4*)(Yhi + o + v*8) = ((int4*)hi16)[v];
                    *(int4*)(Ylo + o + v*8) = ((int4*)lo16)[v];
                }
            }
            __syncthreads();
        }
    }
}

// ---------------- xpre = bn2(regT) + conv(bn1(in)); bn3 partials ----------------
__global__ void __launch_bounds__(256)
k_xpre_r14(const float* __restrict__ regT, const void* __restrict__ in,
           const void* __restrict__ convW, const void* __restrict__ convb,
           const int* __restrict__ dflag, const float* __restrict__ st1,
           const float* __restrict__ st2, float* __restrict__ pb3,
           float* __restrict__ xpre)
{
    int f = *dflag;
    float m1[3], r1[3], m2[3], r2[3], cw[9], cb[3];
    #pragma unroll
    for (int c = 0; c < 3; c++) {
        float m = st1[c] * (1.0f/CNT_PER_C);
        float v = st1[3+c] * (1.0f/CNT_PER_C) - m*m;
        m1[c] = m; r1[c] = 1.0f / sqrtf(v + 1e-5f);
        float mm = st2[c] * (1.0f/CNT_PER_C);
        float vv = st2[3+c] * (1.0f/CNT_PER_C) - mm*mm;
        m2[c] = mm; r2[c] = 1.0f / sqrtf(vv + 1e-5f);
        cb[c] = ldf(convb, c, f);
    }
    #pragma unroll
    for (int j = 0; j < 9; j++) cw[j] = ldf(convW, j, f);
    float s0=0,s1=0,s2=0,q0=0,q1=0,q2=0;
    for (int i = blockIdx.x*256 + threadIdx.x; i < TOT_X; i += 1024*256) {
        int b = i / 31788, r1_ = i % 31788;
        int c = r1_ / NL, r2_ = r1_ % NL;
        int n = r2_ / 12, l = r2_ % 12;
        float hidv = (regT[((size_t)b*NN + n)*36 + c*12 + l] - m2[c]) * r2[c];
        float cx = cb[c];
        #pragma unroll
        for (int cc = 0; cc < 3; cc++) {
            float xbv = (ldf(in, ((long)(b*3 + cc)*NN + n)*12 + l, f) - m1[cc]) * r1[cc];
            cx += cw[c*3 + cc] * xbv;
        }
        float v = hidv + cx;
        xpre[i] = v;
        float v2 = v*v;
        s0 += (c == 0) ? v : 0.f;  q0 += (c == 0) ? v2 : 0.f;
        s1 += (c == 1) ? v : 0.f;  q1 += (c == 1) ? v2 : 0.f;
        s2 += (c == 2) ? v : 0.f;  q2 += (c == 2) ? v2 : 0.f;
    }
    __shared__ float red[6][256];
    int t = threadIdx.x;
    red[0][t] = s0; red[1][t] = s1; red[2][t] = s2;
    red[3][t] = q0; red[4][t] = q1; red[5][t] = q2;
    __syncthreads();
    for (int st_ = 128; st_ > 0; st_ >>= 1) {
        if (t < st_) {
            #pragma unroll
            for (int j = 0; j < 6; j++) red[j][t] += red[j][t+st_];
        }
        __syncthreads();
    }
    if (t < 6) pb3[blockIdx.x*6 + t] = red[t][0];
}

// ---------------- tail per (b,n) ----------------
__global__ void __launch_bounds__(64)
k_tail_r14(const float* __restrict__ xpre, const float* __restrict__ st3,
           const float* __restrict__ phi, const float* __restrict__ topval,
           const int* __restrict__ topidx, const float* __restrict__ wc,
           const void* __restrict__ wie, const void* __restrict__ mixp,
           const int* __restrict__ dflag, float* __restrict__ out)
{
    int f = *dflag;
    int n = blockIdx.x, b = blockIdx.y, t = threadIdx.x;
    __shared__ float xe[3][10][12], mn[3][10], phis[24], ws[10];
    __shared__ float pm[3][10][12], pred[3][12];
    float m3[3], rs3[3];
    #pragma unroll
    for (int c = 0; c < 3; c++) {
        float m = st3[c] * (1.0f/CNT_PER_C);
        float v = st3[3+c] * (1.0f/CNT_PER_C) - m*m;
        m3[c] = m; rs3[c] = 1.0f / sqrtf(v + 1e-5f);
    }
    if (t < 24) phis[t] = phi[b*24 + t];
    if (t < 10) ws[t] = (t == 0 ? 1.0f : topval[n*9 + t - 1]) * ldf(wie, t, f);
    for (int i = t; i < 360; i += 64) {
        int c = i / 120, m = (i / 12) % 10, l = i % 12;
        int nn2 = (m == 0) ? n : topidx[n*9 + m - 1];
        xe[c][m][l] = (xpre[((size_t)(b*3 + c)*NN + nn2)*12 + l] - m3[c]) * rs3[c];
    }
    __syncthreads();
    if (t < 30) {
        int c = t / 10, m = t % 10;
        float s = 0.f;
        #pragma unroll
        for (int l = 0; l < 12; l++) s += xe[c][m][l];
        mn[c][m] = s * (1.0f/12.0f);
    }
    __syncthreads();
    float mix = ldf(mixp, 0, f);
    for (int pr = t; pr < 120; pr += 64) {
        int m = pr / 12, p = pr % 12;
        float y[3], sc[12], mx = -3.4e38f;
        #pragma unroll
        for (int c = 0; c < 3; c++) y[c] = phis[12+p] + mix*mn[c][m];
        #pragma unroll
        for (int l = 0; l < 12; l++) {
            float v = 0.f;
            #pragma unroll
            for (int c = 0; c < 3; c++) v += y[c] * (phis[l] + mix*mn[c][m]);
            sc[l] = v * (1.0f/36.0f); mx = fmaxf(mx, sc[l]);
        }
        float den = 0.f;
        #pragma unroll
        for (int l = 0; l < 12; l++) { float e = expf(sc[l] - mx); sc[l] = e; den += e; }
        float inv = 1.0f/den;
        float p0 = 0.f, p1 = 0.f, p2 = 0.f;
        #pragma unroll
        for (int l = 0; l < 12; l++) {
            float a = sc[l]*inv;
            p0 += a*xe[0][m][l]; p1 += a*xe[1][m][l]; p2 += a*xe[2][m][l];
        }
        pm[0][m][p] = p0; pm[1][m][p] = p1; pm[2][m][p] = p2;
    }
    __syncthreads();
    if (t < 36) {
        int c = t/12, p = t%12;
        float s = 0.f;
        #pragma unroll
        for (int m = 0; m < 10; m++) s += pm[c][m][p]*ws[m];
        pred[c][p] = s;
    }
    __syncthreads();
    if (t < 36) {
        int o = t/12, p = t%12;
        float o1 = wc[9+o]  + wc[o*3+0]*pred[0][p] + wc[o*3+1]*pred[1][p] + wc[o*3+2]*pred[2][p];
        float o2 = wc[21+o] + wc[12+o*3+0]*pred[0][p] + wc[12+o*3+1]*pred[1][p] + wc[12+o*3+2]*pred[2][p];
        out[((size_t)(b*3 + o)*NN + n)*12 + p] = o1 / (1.0f + expf(-o2));
    }
}

// ---------------------------------------------------------------------------
extern "C" void kernel_launch(void* const* d_in, const int* in_sizes, int n_in,
                              void* d_out, int out_size, void* d_ws, size_t ws_size,
                              hipStream_t stream)
{
    (void)in_sizes; (void)n_in;
    char* w = (char*)d_ws;
    auto alloc = [&](size_t bytes) { char* p = w; w += (bytes + 255) & ~(size_t)255; return p; };

    float* regT   = (float*)alloc((size_t)TOT_X*4);
    float* xpre   = (float*)alloc((size_t)TOT_X*4);
    __hip_bfloat16* Whi1 = (__hip_bfloat16*)alloc(786432*2);
    __hip_bfloat16* Wlo1 = (__hip_bfloat16*)alloc(786432*2);
    __hip_bfloat16* Whi2 = (__hip_bfloat16*)alloc(786432*2);
    __hip_bfloat16* Wlo2 = (__hip_bfloat16*)alloc(786432*2);
    __hip_bfloat16* rhi  = (__hip_bfloat16*)alloc(18432*2);
    __hip_bfloat16* rlo  = (__hip_bfloat16*)alloc(18432*2);
    float* e1     = (float*)alloc(113024*4);
    float* e2t    = (float*)alloc(113024*4);
    float* phi    = (float*)alloc(768*4);
    float* topval = (float*)alloc(7947*4);
    int*   topidx = (int*)alloc(7947*4);
    int*   tidx   = (int*)alloc(32*4);
    int*   didx   = (int*)alloc(32*4);
    float* stats  = (float*)alloc(18*4);
    float* wc     = (float*)alloc(24*4);
    int*   dflag  = (int*)alloc(4);
    float* pb1    = (float*)alloc(512*6*4);
    float* pb2    = (float*)alloc(224*6*4);
    float* pb3    = (float*)alloc(1024*6*4);
    size_t fixedEnd = (size_t)(w - (char*)d_ws);

    const size_t XB = (size_t)NPAD*HH*2;
    int CH = 0;
    for (int c = 32; c >= 1; c >>= 1) {
        if (fixedEnd + 4*(size_t)c*XB + 4096 <= ws_size) { CH = c; break; }
    }
    if (CH == 0) {
        k_sent_r14<<<(out_size + 255)/256, 256, 0, stream>>>((float*)d_out, out_size);
        return;
    }
    char* regionB = w;
    __hip_bfloat16* Xahi = (__hip_bfloat16*)regionB;
    __hip_bfloat16* Xalo = (__hip_bfloat16*)(regionB + (size_t)CH*XB);
    __hip_bfloat16* Xbhi = (__hip_bfloat16*)(regionB + 2*(size_t)CH*XB);
    __hip_bfloat16* Xblo = (__hip_bfloat16*)(regionB + 3*(size_t)CH*XB);

    k_probe_r14<<<1, 256, 0, stream>>>((const unsigned short*)d_in[0], dflag);
    k_prep_r14<<<1, 256, 0, stream>>>(d_in[2], d_in[3], d_in[19], d_in[20], d_in[21], d_in[22],
                                      d_in[25], d_in[26], d_in[27], d_in[28], d_in[29], d_in[30],
                                      dflag, tidx, didx, phi, wc);
    k_wsplit_r14<<<1024, 256, 0, stream>>>(d_in[13], dflag, 786432, Whi1, Wlo1);
    k_wsplit_r14<<<1024, 256, 0, stream>>>(d_in[15], dflag, 786432, Whi2, Wlo2);
    k_wsplit_r14<<<72,   256, 0, stream>>>(d_in[17], dflag, 18432, rhi, rlo);

    k_e_r14<<<883, 256, 0, stream>>>(d_in[4], d_in[5], d_in[6], dflag, e1, e2t);
    k_graph_r14<<<883, 256, 0, stream>>>(e1, e2t, topval, topidx);
    k_bn1_r14<<<512, 256, 0, stream>>>(d_in[0], dflag, pb1);
    k_fin_r14<<<1, 256, 0, stream>>>(pb1, 512, stats);

    for (int b0 = 0; b0 < BB; b0 += CH) {
        k_hid_r14<<<dim3(111, CH), 256, 0, stream>>>(d_in[0], d_in[4], d_in[7], d_in[8],
                                                     d_in[9], d_in[10], tidx, didx, dflag,
                                                     stats, b0, Xahi, Xalo);
        for (int i = 0; i < 3; i++) {
            k_gemm_r14<true, false, false><<<dim3(7, 4, CH), 256, 0, stream>>>(
                Whi1, Wlo1, (long)i*HH*HH, d_in[14], (long)i*HH, dflag,
                Xahi, Xalo, Xbhi, Xblo, (float*)nullptr, (float*)nullptr, HH, b0);
            k_gemm_r14<false, true, false><<<dim3(7, 4, CH), 256, 0, stream>>>(
                Whi2, Wlo2, (long)i*HH*HH, d_in[16], (long)i*HH, dflag,
                Xbhi, Xblo, Xahi, Xalo, (float*)nullptr, (float*)nullptr, HH, b0);
        }
        k_gemm_r14<false, false, true><<<dim3(7, 1, CH), 256, 0, stream>>>(
            rhi, rlo, 0, d_in[18], 0, dflag,
            Xahi, Xalo, (__hip_bfloat16*)nullptr, (__hip_bfloat16*)nullptr,
            regT, pb2, 36, b0);
    }
    k_fin_r14<<<1, 256, 0, stream>>>(pb2, 224, stats + 6);

    k_xpre_r14<<<1024, 256, 0, stream>>>(regT, d_in[0], d_in[11], d_in[12], dflag,
                                         stats, stats + 6, pb3, xpre);
    k_fin_r14<<<1, 256, 0, stream>>>(pb3, 1024, stats + 12);

    k_tail_r14<<<dim3(NN, BB), 64, 0, stream>>>(xpre, stats + 12, phi, topval, topidx, wc,
                                                d_in[24], d_in[23], dflag, (float*)d_out);
}